// Round 1
// baseline (536.177 us; speedup 1.0000x reference)
//
#include <hip/hip_runtime.h>

// self_attention: B=4, C=512, C8=64, N=64*64=4096
//   f = x^T Wf^T + bf   (B,N,64)
//   g = x^T Wg^T + bg   (B,N,64)  (token-major; only used as logits)
//   S[i,j] = f[i,:].g[j,:]        (std ~8, |S| <= ~45 -> exp fits fp32/bf16)
//   l_i = sum_j exp(S[i,j])       (no max-subtract needed)
//   hv2[c,i] = (x^T Wh^T + bh)[c,i] / l_i          (bf16)
//   out[c,j] = gamma * sum_i hv2[c,i]*exp(S[i,j]) + x[c,j]
// Precision: split-bf16 (hi+lo, 3 MFMAs) for f/g and S; plain bf16 for hv/sa.
// Workspace: ~57 MB.

#define Bq 4
#define Cq 512
#define Nq 4096

typedef __attribute__((ext_vector_type(8))) short bf16x8;
typedef __attribute__((ext_vector_type(4))) short bf16x4;
typedef __attribute__((ext_vector_type(4))) float f32x4;

__device__ __forceinline__ short f2bf(float f) {
  unsigned u = __float_as_uint(f);
  u += 0x7fffu + ((u >> 16) & 1u);   // RNE
  return (short)(u >> 16);
}
__device__ __forceinline__ float bf2f(short h) {
  return __uint_as_float(((unsigned)(unsigned short)h) << 16);
}

#define MFMA16(A, B, C) __builtin_amdgcn_mfma_f32_16x16x32_bf16((A), (B), (C), 0, 0, 0)

// ---------------- K_prepw: W splits ----------------
// whi/wlo: rows 0..63 = Wf, 64..127 = Wg  ([o][c], c contig). whb = bf16(Wh).
__global__ __launch_bounds__(256) void k_prepw(
    const float* __restrict__ Wf, const float* __restrict__ Wg,
    const float* __restrict__ Wh,
    short* __restrict__ whi, short* __restrict__ wlo, short* __restrict__ whb) {
  int gid = blockIdx.x * 256 + threadIdx.x;  // 0..262143
  if (gid < 128 * 512) {
    int row = gid >> 9;
    float v = (row < 64) ? Wf[gid] : Wg[gid - 32768];
    short h = f2bf(v);
    whi[gid] = h;
    wlo[gid] = f2bf(v - bf2f(h));
  }
  whb[gid] = f2bf(Wh[gid]);
}

// ---------------- K_xpose: x (B,C,N) fp32 -> XT (B,N,C) bf16 hi/lo ----------------
__global__ __launch_bounds__(256) void k_xpose(
    const float* __restrict__ x, short* __restrict__ xthi, short* __restrict__ xtlo) {
  int b = blockIdx.z, c0 = blockIdx.y * 64, n0 = blockIdx.x * 64;
  __shared__ float tile[64][65];
  int t = threadIdx.x;
  int l = t & 15, g = t >> 4;  // g in 0..15
  const float* xp = x + ((size_t)b * Cq + c0) * Nq + n0;
#pragma unroll
  for (int e = 0; e < 4; e++) {
    int cl = g + e * 16;
    float4 v = *(const float4*)(xp + (size_t)cl * Nq + l * 4);
    tile[cl][l * 4 + 0] = v.x; tile[cl][l * 4 + 1] = v.y;
    tile[cl][l * 4 + 2] = v.z; tile[cl][l * 4 + 3] = v.w;
  }
  __syncthreads();
#pragma unroll
  for (int e = 0; e < 4; e++) {
    int nl = g + e * 16;
    short hi[4], lo[4];
#pragma unroll
    for (int qq = 0; qq < 4; qq++) {
      float v = tile[l * 4 + qq][nl];
      hi[qq] = f2bf(v);
      lo[qq] = f2bf(v - bf2f(hi[qq]));
    }
    size_t off = ((size_t)b * Nq + n0 + nl) * Cq + c0 + l * 4;
    *(short4*)(xthi + off) = make_short4(hi[0], hi[1], hi[2], hi[3]);
    *(short4*)(xtlo + off) = make_short4(lo[0], lo[1], lo[2], lo[3]);
  }
}

// ---------------- K_fg: f,g GEMM (split-bf16 x split-bf16, 3 MFMAs) ----------------
// out: fhi/flo[b][n][64], ghi/glo[b][n][64]  (token-major, o contig)
__global__ __launch_bounds__(512) void k_fg(
    const short* __restrict__ xthi, const short* __restrict__ xtlo,
    const short* __restrict__ whi, const short* __restrict__ wlo,
    const float* __restrict__ bfv, const float* __restrict__ bgv,
    short* __restrict__ fhi, short* __restrict__ flo,
    short* __restrict__ ghi, short* __restrict__ glo) {
  int b = blockIdx.y, n0 = blockIdx.x * 64;
  int t = threadIdx.x, w = t >> 6, lane = t & 63, l15 = lane & 15, q = lane >> 4;
  int wr = w & 3, wh = w >> 2;  // row group / o-half (0=f,1=g)
  const short* ah = xthi + ((size_t)b * Nq + n0 + wr * 16 + l15) * Cq;
  const short* al = xtlo + ((size_t)b * Nq + n0 + wr * 16 + l15) * Cq;
  f32x4 z = {0.f, 0.f, 0.f, 0.f};
  f32x4 acc[4] = {z, z, z, z};
  for (int ks = 0; ks < 16; ks++) {
    bf16x8 Ahi = *(const bf16x8*)(ah + ks * 32 + q * 8);
    bf16x8 Alo = *(const bf16x8*)(al + ks * 32 + q * 8);
#pragma unroll
    for (int os = 0; os < 4; os++) {
      int o = wh * 64 + os * 16 + l15;
      bf16x8 Bhi = *(const bf16x8*)(whi + o * 512 + ks * 32 + q * 8);
      bf16x8 Blo = *(const bf16x8*)(wlo + o * 512 + ks * 32 + q * 8);
      acc[os] = MFMA16(Alo, Bhi, acc[os]);
      acc[os] = MFMA16(Ahi, Blo, acc[os]);
      acc[os] = MFMA16(Ahi, Bhi, acc[os]);
    }
  }
#pragma unroll
  for (int os = 0; os < 4; os++) {
#pragma unroll
    for (int r = 0; r < 4; r++) {
      int og = wh * 64 + os * 16 + l15;
      int n = n0 + wr * 16 + q * 4 + r;
      float v = acc[os][r];
      if (wh == 0) {
        v += bfv[og];
        size_t off = ((size_t)b * Nq + n) * 64 + og;
        short h = f2bf(v);
        fhi[off] = h; flo[off] = f2bf(v - bf2f(h));
      } else {
        int o2 = og - 64;
        v += bgv[o2];
        size_t off = ((size_t)b * Nq + n) * 64 + o2;
        short h = f2bf(v);
        ghi[off] = h; glo[off] = f2bf(v - bf2f(h));
      }
    }
  }
}

// ---------------- K_stats: l_i = sum_j exp(S[i,j]); store 1/l ----------------
__global__ __launch_bounds__(512) void k_stats(
    const short* __restrict__ fhi, const short* __restrict__ flo,
    const short* __restrict__ ghi, const short* __restrict__ glo,
    float* __restrict__ linv) {
  int b = blockIdx.y, i0 = blockIdx.x * 64;
  int t = threadIdx.x, w = t >> 6, lane = t & 63, l15 = lane & 15, q = lane >> 4;
  int wr = w & 3, jh = w >> 2;
  const short* fh = fhi + ((size_t)b * Nq + i0 + wr * 16 + l15) * 64;
  const short* fl = flo + ((size_t)b * Nq + i0 + wr * 16 + l15) * 64;
  bf16x8 Ahi[2], Alo[2];
  Ahi[0] = *(const bf16x8*)(fh + q * 8);
  Ahi[1] = *(const bf16x8*)(fh + 32 + q * 8);
  Alo[0] = *(const bf16x8*)(fl + q * 8);
  Alo[1] = *(const bf16x8*)(fl + 32 + q * 8);
  float ls[4] = {0.f, 0.f, 0.f, 0.f};
  for (int jt = 0; jt < 32; jt++) {
    int jb = jt * 128 + jh * 64;
#pragma unroll
    for (int js = 0; js < 4; js++) {
      int j = jb + js * 16 + l15;
      const short* gh = ghi + ((size_t)b * Nq + j) * 64;
      const short* gl = glo + ((size_t)b * Nq + j) * 64;
      f32x4 s = {0.f, 0.f, 0.f, 0.f};
#pragma unroll
      for (int ss = 0; ss < 2; ss++) {
        bf16x8 Bhi = *(const bf16x8*)(gh + ss * 32 + q * 8);
        bf16x8 Blo = *(const bf16x8*)(gl + ss * 32 + q * 8);
        s = MFMA16(Alo[ss], Bhi, s);
        s = MFMA16(Ahi[ss], Blo, s);
        s = MFMA16(Ahi[ss], Bhi, s);
      }
      ls[0] += __expf(s[0]); ls[1] += __expf(s[1]);
      ls[2] += __expf(s[2]); ls[3] += __expf(s[3]);
    }
  }
#pragma unroll
  for (int m = 1; m < 16; m <<= 1) {
    ls[0] += __shfl_xor(ls[0], m, 64);
    ls[1] += __shfl_xor(ls[1], m, 64);
    ls[2] += __shfl_xor(ls[2], m, 64);
    ls[3] += __shfl_xor(ls[3], m, 64);
  }
  __shared__ float part[2][64];
  if (l15 == 0) {
#pragma unroll
    for (int r = 0; r < 4; r++) part[jh][wr * 16 + q * 4 + r] = ls[r];
  }
  __syncthreads();
  if (t < 64) {
    linv[(size_t)b * Nq + i0 + t] = 1.0f / (part[0][t] + part[1][t]);
  }
}

// ---------------- K_hv: hv2[b][c][i] = bf16((Wh.x + bh) * linv[i]) ----------------
__global__ __launch_bounds__(256) void k_hv(
    const short* __restrict__ whb, const short* __restrict__ xthi,
    const float* __restrict__ bhv, const float* __restrict__ linv,
    short* __restrict__ hv2) {
  int b = blockIdx.z, c0 = blockIdx.y * 64, i0 = blockIdx.x * 64;
  int t = threadIdx.x, w = t >> 6, lane = t & 63, l15 = lane & 15, q = lane >> 4;
  const short* ar = whb + (size_t)(c0 + w * 16 + l15) * 512;
  const short* br = xthi + ((size_t)b * Nq + i0) * Cq;
  f32x4 z = {0.f, 0.f, 0.f, 0.f};
  f32x4 acc[4] = {z, z, z, z};
  for (int ks = 0; ks < 16; ks++) {
    bf16x8 A = *(const bf16x8*)(ar + ks * 32 + q * 8);
#pragma unroll
    for (int is = 0; is < 4; is++) {
      bf16x8 Bv = *(const bf16x8*)(br + (size_t)(is * 16 + l15) * Cq + ks * 32 + q * 8);
      acc[is] = MFMA16(A, Bv, acc[is]);
    }
  }
#pragma unroll
  for (int is = 0; is < 4; is++) {
#pragma unroll
    for (int r = 0; r < 4; r++) {
      int c = c0 + w * 16 + q * 4 + r;
      int i = i0 + is * 16 + l15;
      float v = acc[is][r] + bhv[c];
      v *= linv[(size_t)b * Nq + i];
      hv2[((size_t)b * Cq + c) * Nq + i] = f2bf(v);
    }
  }
}

// ---------------- K_attn: out = gamma * hv2 @ exp(S) + x ----------------
// 256 blocks (XCD-swizzled: batch b -> XCD pair), 512 thr. Block: all 512 c x 64 j.
__global__ __launch_bounds__(512) void k_attn(
    const short* __restrict__ fhi, const short* __restrict__ flo,
    const short* __restrict__ ghi, const short* __restrict__ glo,
    const short* __restrict__ hv2, const float* __restrict__ x,
    const float* __restrict__ gp, float* __restrict__ out) {
  int L = blockIdx.x;
  int b = (L & 7) >> 1;                      // batch -> XCD pair (L%8 heuristic)
  int jt = ((L >> 3) << 1) | (L & 1);
  int j0 = jt * 64;
  int t = threadIdx.x, w = t >> 6, lane = t & 63, l15 = lane & 15, q = lane >> 4;
  int wr = w & 3, jh = w >> 2;               // S row-group / j-half
  __shared__ short pt[64 * 68];              // P^T tile [j][i], stride 68 shorts (136 B)
  float gamma = gp[0];
  f32x4 z = {0.f, 0.f, 0.f, 0.f};
  f32x4 acc[4][4];                           // [csub][jsub]
#pragma unroll
  for (int a = 0; a < 4; a++)
#pragma unroll
    for (int bb = 0; bb < 4; bb++) acc[a][bb] = z;
  // Hoist loop-invariant G fragments (B-operand of S) into registers.
  bf16x8 GB[2][2][2];                        // [jsub_own][kstep][hi/lo]
#pragma unroll
  for (int js = 0; js < 2; js++) {
    int j = j0 + jh * 32 + js * 16 + l15;
    const short* gh = ghi + ((size_t)b * Nq + j) * 64;
    const short* gl = glo + ((size_t)b * Nq + j) * 64;
#pragma unroll
    for (int ss = 0; ss < 2; ss++) {
      GB[js][ss][0] = *(const bf16x8*)(gh + ss * 32 + q * 8);
      GB[js][ss][1] = *(const bf16x8*)(gl + ss * 32 + q * 8);
    }
  }
  const short* hvb = hv2 + ((size_t)b * Cq + w * 64) * Nq;  // wave's 64-c strip
  for (int it = 0; it < 64; it++) {
    int i0 = it * 64;
    const short* fh = fhi + ((size_t)b * Nq + i0 + wr * 16 + l15) * 64;
    const short* fl = flo + ((size_t)b * Nq + i0 + wr * 16 + l15) * 64;
    f32x4 s[2] = {z, z};
#pragma unroll
    for (int ss = 0; ss < 2; ss++) {
      bf16x8 Ahi = *(const bf16x8*)(fh + ss * 32 + q * 8);
      bf16x8 Alo = *(const bf16x8*)(fl + ss * 32 + q * 8);
#pragma unroll
      for (int js = 0; js < 2; js++) {
        s[js] = MFMA16(Alo, GB[js][ss][0], s[js]);
        s[js] = MFMA16(Ahi, GB[js][ss][1], s[js]);
        s[js] = MFMA16(Ahi, GB[js][ss][0], s[js]);
      }
    }
    __syncthreads();  // prior iter's pt reads complete
#pragma unroll
    for (int js = 0; js < 2; js++) {
      int jl = jh * 32 + js * 16 + l15;
      int il = wr * 16 + q * 4;
      unsigned p01 = (unsigned)(unsigned short)f2bf(__expf(s[js][0])) |
                     ((unsigned)(unsigned short)f2bf(__expf(s[js][1])) << 16);
      unsigned p23 = (unsigned)(unsigned short)f2bf(__expf(s[js][2])) |
                     ((unsigned)(unsigned short)f2bf(__expf(s[js][3])) << 16);
      *(unsigned*)(pt + jl * 68 + il) = p01;
      *(unsigned*)(pt + jl * 68 + il + 2) = p23;
    }
    __syncthreads();  // pt ready
#pragma unroll
    for (int ss = 0; ss < 2; ss++) {
      bf16x8 PB[4];
#pragma unroll
      for (int js = 0; js < 4; js++) {
        const short* pp = pt + (js * 16 + l15) * 68 + ss * 32 + q * 8;
        bf16x4 a4 = *(const bf16x4*)pp;
        bf16x4 b4 = *(const bf16x4*)(pp + 4);
        PB[js] = __builtin_shufflevector(a4, b4, 0, 1, 2, 3, 4, 5, 6, 7);
      }
#pragma unroll
      for (int cs = 0; cs < 4; cs++) {
        bf16x8 A = *(const bf16x8*)(hvb + (size_t)(cs * 16 + l15) * Nq + i0 + ss * 32 + q * 8);
#pragma unroll
        for (int js = 0; js < 4; js++)
          acc[cs][js] = MFMA16(A, PB[js], acc[cs][js]);
      }
    }
  }
#pragma unroll
  for (int cs = 0; cs < 4; cs++) {
#pragma unroll
    for (int js = 0; js < 4; js++) {
#pragma unroll
      for (int r = 0; r < 4; r++) {
        int c = w * 64 + cs * 16 + q * 4 + r;
        int j = j0 + js * 16 + l15;
        size_t off = ((size_t)b * Cq + c) * Nq + j;
        out[off] = gamma * acc[cs][js][r] + x[off];
      }
    }
  }
}

extern "C" void kernel_launch(void* const* d_in, const int* in_sizes, int n_in,
                              void* d_out, int out_size, void* d_ws, size_t ws_size,
                              hipStream_t stream) {
  (void)in_sizes; (void)n_in; (void)out_size; (void)ws_size;
  const float* x  = (const float*)d_in[0];
  const float* Wf = (const float*)d_in[1];
  const float* bf = (const float*)d_in[2];
  const float* Wg = (const float*)d_in[3];
  const float* bg = (const float*)d_in[4];
  const float* Wh = (const float*)d_in[5];
  const float* bh = (const float*)d_in[6];
  const float* gm = (const float*)d_in[7];
  float* out = (float*)d_out;
  char* ws = (char*)d_ws;
  // Workspace layout (bytes); total = 59,572,224 (~57 MB)
  short* xthi = (short*)(ws);               // 16,777,216  (B,N,C) bf16 hi
  short* xtlo = (short*)(ws + 16777216);    // 16,777,216  lo
  short* fhi  = (short*)(ws + 33554432);    //  2,097,152  (B,N,64)
  short* flo  = (short*)(ws + 35651584);    //  2,097,152
  short* ghi  = (short*)(ws + 37748736);    //  2,097,152  (B,N,64) token-major
  short* glo  = (short*)(ws + 39845888);    //  2,097,152
  short* whi  = (short*)(ws + 41943040);    //    131,072  (128,512)
  short* wlo  = (short*)(ws + 42074112);    //    131,072
  short* whb  = (short*)(ws + 42205184);    //    524,288  (512,512)
  float* linv = (float*)(ws + 42729472);    //     65,536  (B,N)
  short* hv2  = (short*)(ws + 42795008);    // 16,777,216  (B,C,N) bf16

  hipLaunchKernelGGL(k_prepw, dim3(1024), dim3(256), 0, stream, Wf, Wg, Wh, whi, wlo, whb);
  hipLaunchKernelGGL(k_xpose, dim3(64, 8, 4), dim3(256), 0, stream, x, xthi, xtlo);
  hipLaunchKernelGGL(k_fg, dim3(64, 4), dim3(512), 0, stream,
                     xthi, xtlo, whi, wlo, bf, bg, fhi, flo, ghi, glo);
  hipLaunchKernelGGL(k_stats, dim3(64, 4), dim3(512), 0, stream, fhi, flo, ghi, glo, linv);
  hipLaunchKernelGGL(k_hv, dim3(64, 8, 4), dim3(256), 0, stream, whb, xthi, bh, linv, hv2);
  hipLaunchKernelGGL(k_attn, dim3(256), dim3(512), 0, stream,
                     fhi, flo, ghi, glo, hv2, x, gm, out);
}